// Round 1
// baseline (1961.630 us; speedup 1.0000x reference)
//
#include <hip/hip_runtime.h>

#define B_TOTAL 4096
#define T_STEPS 512
#define F_IN    32
#define H_DIM   60
#define G_DIM   240   // 4*H
#define KW      92    // F+H
#define BC      16    // batch rows per block

__device__ __forceinline__ float fast_sig(float z) {
    return 1.0f / (1.0f + __expf(-z));
}
__device__ __forceinline__ float fast_tanh(float z) {
    // tanh(z) = 1 - 2/(exp(2z)+1); saturates correctly for |z| large
    return 1.0f - 2.0f / (1.0f + __expf(2.0f * z));
}

__global__ __launch_bounds__(256, 1)
void lstm_fused_kernel(const float* __restrict__ x,
                       const float* __restrict__ kernel,
                       const float* __restrict__ bias,
                       const float* __restrict__ dense_w,
                       const float* __restrict__ dense_b,
                       float* __restrict__ out)
{
    // Weights interleaved: Wl[k*240 + u*4 + gate], gate in {i,j,f,o}
    __shared__ float Wl[KW * G_DIM];          // 88320 B
    __shared__ float xs[2][BC][F_IN];         // 4096 B (double buffered)
    __shared__ float hs[BC][H_DIM];           // 3840 B

    const int tid = threadIdx.x;
    const int b0  = blockIdx.x * BC;
    const int u   = tid & 63;    // hidden unit (active if < 60)
    const int bg  = tid >> 6;    // batch group: rows bg*4 .. bg*4+3
    const bool active = (u < H_DIM);

    // ---- stage weights, re-interleaving gates into float4 per (k,u) ----
    for (int idx = tid; idx < KW * G_DIM; idx += 256) {
        int k    = idx / G_DIM;
        int col  = idx - k * G_DIM;
        int gate = col / H_DIM;
        int uu   = col - gate * H_DIM;
        Wl[k * G_DIM + uu * 4 + gate] = kernel[idx];
    }
    // ---- init h = 0 ----
    for (int idx = tid; idx < BC * H_DIM; idx += 256) {
        (&hs[0][0])[idx] = 0.0f;
    }
    // ---- stage x for t=0 ----
    if (tid < 128) {
        int row = tid >> 3, kq = tid & 7;
        float4 v = *reinterpret_cast<const float4*>(
            x + (size_t)(b0 + row) * (T_STEPS * F_IN) + kq * 4);
        *reinterpret_cast<float4*>(&xs[0][row][kq * 4]) = v;
    }

    float bi = 0.f, bj = 0.f, bf = 0.f, bo = 0.f;
    if (active) {
        bi = bias[u];
        bj = bias[H_DIM + u];
        bf = bias[2 * H_DIM + u];
        bo = bias[3 * H_DIM + u];
    }
    float c[4] = {0.f, 0.f, 0.f, 0.f};

    __syncthreads();

    int cur = 0;
    for (int t = 0; t < T_STEPS; ++t) {
        // ---- prefetch x(t+1) into registers (latency hidden by compute) ----
        float4 vx;
        int prow = 0, pkq = 0;
        if (tid < 128) {
            prow = tid >> 3; pkq = tid & 7;
            int tn = (t + 1 < T_STEPS) ? (t + 1) : t;
            vx = *reinterpret_cast<const float4*>(
                x + (size_t)(b0 + prow) * (T_STEPS * F_IN) + tn * F_IN + pkq * 4);
        }

        float ai[4], aj[4], af[4], ao[4];
        if (active) {
            #pragma unroll
            for (int r = 0; r < 4; ++r) { ai[r] = bi; aj[r] = bj; af[r] = bf; ao[r] = bo; }

            // ---- x contribution: k = 0..31 ----
            #pragma unroll
            for (int kq = 0; kq < 8; ++kq) {
                float4 w0 = *reinterpret_cast<const float4*>(&Wl[(kq * 4 + 0) * G_DIM + u * 4]);
                float4 w1 = *reinterpret_cast<const float4*>(&Wl[(kq * 4 + 1) * G_DIM + u * 4]);
                float4 w2 = *reinterpret_cast<const float4*>(&Wl[(kq * 4 + 2) * G_DIM + u * 4]);
                float4 w3 = *reinterpret_cast<const float4*>(&Wl[(kq * 4 + 3) * G_DIM + u * 4]);
                #pragma unroll
                for (int r = 0; r < 4; ++r) {
                    int row = bg * 4 + r;
                    float4 v = *reinterpret_cast<const float4*>(&xs[cur][row][kq * 4]);
                    ai[r] = fmaf(v.x, w0.x, fmaf(v.y, w1.x, fmaf(v.z, w2.x, fmaf(v.w, w3.x, ai[r]))));
                    aj[r] = fmaf(v.x, w0.y, fmaf(v.y, w1.y, fmaf(v.z, w2.y, fmaf(v.w, w3.y, aj[r]))));
                    af[r] = fmaf(v.x, w0.z, fmaf(v.y, w1.z, fmaf(v.z, w2.z, fmaf(v.w, w3.z, af[r]))));
                    ao[r] = fmaf(v.x, w0.w, fmaf(v.y, w1.w, fmaf(v.z, w2.w, fmaf(v.w, w3.w, ao[r]))));
                }
            }
            // ---- h contribution: k = 32..91 (j = 0..59) ----
            #pragma unroll
            for (int jq = 0; jq < 15; ++jq) {
                float4 w0 = *reinterpret_cast<const float4*>(&Wl[(F_IN + jq * 4 + 0) * G_DIM + u * 4]);
                float4 w1 = *reinterpret_cast<const float4*>(&Wl[(F_IN + jq * 4 + 1) * G_DIM + u * 4]);
                float4 w2 = *reinterpret_cast<const float4*>(&Wl[(F_IN + jq * 4 + 2) * G_DIM + u * 4]);
                float4 w3 = *reinterpret_cast<const float4*>(&Wl[(F_IN + jq * 4 + 3) * G_DIM + u * 4]);
                #pragma unroll
                for (int r = 0; r < 4; ++r) {
                    int row = bg * 4 + r;
                    float4 v = *reinterpret_cast<const float4*>(&hs[row][jq * 4]);
                    ai[r] = fmaf(v.x, w0.x, fmaf(v.y, w1.x, fmaf(v.z, w2.x, fmaf(v.w, w3.x, ai[r]))));
                    aj[r] = fmaf(v.x, w0.y, fmaf(v.y, w1.y, fmaf(v.z, w2.y, fmaf(v.w, w3.y, aj[r]))));
                    af[r] = fmaf(v.x, w0.z, fmaf(v.y, w1.z, fmaf(v.z, w2.z, fmaf(v.w, w3.z, af[r]))));
                    ao[r] = fmaf(v.x, w0.w, fmaf(v.y, w1.w, fmaf(v.z, w2.w, fmaf(v.w, w3.w, ao[r]))));
                }
            }
        }

        __syncthreads();   // all reads of xs[cur] and hs are done

        if (active) {
            #pragma unroll
            for (int r = 0; r < 4; ++r) {
                int row = bg * 4 + r;
                float ig = fast_sig(ai[r]);
                float jg = fast_tanh(aj[r]);
                float fg = fast_sig(af[r] + 1.0f);   // forget bias = 1.0
                float og = fast_sig(ao[r]);
                c[r] = c[r] * fg + ig * jg;
                hs[row][u] = fast_tanh(c[r]) * og;
            }
        }
        if (tid < 128) {
            *reinterpret_cast<float4*>(&xs[cur ^ 1][prow][pkq * 4]) = vx;
        }
        __syncthreads();   // new h and next x visible
        cur ^= 1;
    }

    // ---- epilogue: out[b] = h . dense_w + dense_b ----
    if (tid < BC) {
        float acc = dense_b[0];
        #pragma unroll 4
        for (int uu = 0; uu < H_DIM; ++uu)
            acc = fmaf(hs[tid][uu], dense_w[uu], acc);
        out[b0 + tid] = acc;
    }
}

extern "C" void kernel_launch(void* const* d_in, const int* in_sizes, int n_in,
                              void* d_out, int out_size, void* d_ws, size_t ws_size,
                              hipStream_t stream) {
    const float* x       = (const float*)d_in[0];
    const float* kernel  = (const float*)d_in[1];
    const float* bias    = (const float*)d_in[2];
    const float* dense_w = (const float*)d_in[3];
    const float* dense_b = (const float*)d_in[4];
    float* out = (float*)d_out;

    lstm_fused_kernel<<<B_TOTAL / BC, 256, 0, stream>>>(
        x, kernel, bias, dense_w, dense_b, out);
}

// Round 2
// 746.742 us; speedup vs baseline: 2.6269x; 2.6269x over previous
//
#include <hip/hip_runtime.h>

typedef short short8  __attribute__((ext_vector_type(8)));
typedef short short4v __attribute__((ext_vector_type(4)));
typedef float f32x4   __attribute__((ext_vector_type(4)));

#define B_TOTAL 4096
#define T_STEPS 512
#define F_IN    32
#define H_DIM   60
#define KW      92      // F + H
#define GPAD    260     // gates row pitch (floats); cols 0..255 used
#define UPITCH  104     // U row pitch (halves); 96 used + pad for bank spread

__device__ __forceinline__ unsigned short bf16hi(float f) {
    unsigned int u = __float_as_uint(f);
    u += 0x7FFFu + ((u >> 16) & 1u);          // round to nearest even
    return (unsigned short)(u >> 16);
}
__device__ __forceinline__ float bf16tof(unsigned short s) {
    return __uint_as_float(((unsigned int)s) << 16);
}
__device__ __forceinline__ float fast_sig(float z) {
    return 1.0f / (1.0f + __expf(-z));
}
__device__ __forceinline__ float fast_tanh(float z) {
    return 1.0f - 2.0f / (1.0f + __expf(2.0f * z));
}

__global__ __launch_bounds__(256, 1)
void lstm_mfma_kernel(const float* __restrict__ x,
                      const float* __restrict__ wk,
                      const float* __restrict__ bias,
                      const float* __restrict__ dense_w,
                      const float* __restrict__ dense_b,
                      float* __restrict__ out)
{
    __shared__ float gates[16][GPAD];       // 16.6 KB, col c = u*4+gate
    __shared__ float hsf[16][64];           // final-step h (f32)
    __shared__ short Uhi[16][UPITCH];       // [x_t | h] bf16 hi, k padded to 96
    __shared__ short Ulo[16][UPITCH];       // bf16 lo (residual)

    const int tid  = threadIdx.x;
    const int lane = tid & 63;
    const int w    = tid >> 6;              // wave id 0..3
    const int b0   = blockIdx.x * 16;
    const int lm   = lane & 15;             // M/N lane index
    const int lk8  = (lane >> 4) * 8;       // K sub-block base

    // ---------------- prologue: B fragments (static weights) ----------------
    // Interleaved col c = u*4 + gate (gate order i,j,f,o); original kernel
    // layout is [k][gate*60 + u]. Split each weight into bf16 hi + lo.
    short8 bh[4][3], bl[4][3];
    float  biasv[4];
    #pragma unroll
    for (int tt = 0; tt < 4; ++tt) {
        const int n = w * 4 + tt;           // N-tile 0..15 (15 = zero pad)
        const int c = 16 * n + lm;
        const int u = c >> 2, g = c & 3;
        biasv[tt] = (c < 240) ? bias[g * 60 + u] : 0.0f;
        #pragma unroll
        for (int s = 0; s < 3; ++s) {
            short8 hv, lv;
            #pragma unroll
            for (int e = 0; e < 8; ++e) {
                const int k = s * 32 + lk8 + e;
                float wv = (k < KW && c < 240) ? wk[k * 240 + g * 60 + u] : 0.0f;
                unsigned short hh = bf16hi(wv);
                hv[e] = (short)hh;
                lv[e] = (short)bf16hi(wv - bf16tof(hh));
            }
            bh[tt][s] = hv;
            bl[tt][s] = lv;
        }
    }

    // ---------------- init U (zeros => h0 = 0 and K-pad = 0), stage x(0) ----
    for (int i = tid; i < 16 * UPITCH; i += 256) {
        (&Uhi[0][0])[i] = 0;
        (&Ulo[0][0])[i] = 0;
    }
    __syncthreads();
    if (tid < 128) {
        const int row = tid >> 3, kq = tid & 7;
        float4 v = *reinterpret_cast<const float4*>(
            x + (size_t)(b0 + row) * (T_STEPS * F_IN) + kq * 4);
        float vv[4] = {v.x, v.y, v.z, v.w};
        short4v hv, lv;
        #pragma unroll
        for (int j = 0; j < 4; ++j) {
            unsigned short hh = bf16hi(vv[j]);
            hv[j] = (short)hh;
            lv[j] = (short)bf16hi(vv[j] - bf16tof(hh));
        }
        *reinterpret_cast<short4v*>(&Uhi[row][kq * 4]) = hv;
        *reinterpret_cast<short4v*>(&Ulo[row][kq * 4]) = lv;
    }

    float cst[4] = {0.f, 0.f, 0.f, 0.f};    // cell state: (u=lane, rows w*4+r)
    __syncthreads();

    // ---------------- T loop ----------------
    for (int t = 0; t < T_STEPS; ++t) {
        // prefetch x(t+1) -> registers (latency hides under MFMA + barrier)
        float4 vx;
        int prow = 0, pkq = 0;
        if (tid < 128) {
            prow = tid >> 3; pkq = tid & 7;
            const int tn = (t + 1 < T_STEPS) ? (t + 1) : t;
            vx = *reinterpret_cast<const float4*>(
                x + (size_t)(b0 + prow) * (T_STEPS * F_IN) + tn * F_IN + pkq * 4);
        }

        // A fragments (hi/lo) for the 3 K-steps
        short8 ah[3], al[3];
        #pragma unroll
        for (int s = 0; s < 3; ++s) {
            ah[s] = *reinterpret_cast<const short8*>(&Uhi[lm][s * 32 + lk8]);
            al[s] = *reinterpret_cast<const short8*>(&Ulo[lm][s * 32 + lk8]);
        }

        // gates = U @ W  (bf16x2: hi*hi + lo*hi + hi*lo), bias preloaded
        #pragma unroll
        for (int tt = 0; tt < 4; ++tt) {
            f32x4 acc = {biasv[tt], biasv[tt], biasv[tt], biasv[tt]};
            #pragma unroll
            for (int s = 0; s < 3; ++s) {
                acc = __builtin_amdgcn_mfma_f32_16x16x32_bf16(ah[s], bh[tt][s], acc, 0, 0, 0);
                acc = __builtin_amdgcn_mfma_f32_16x16x32_bf16(al[s], bh[tt][s], acc, 0, 0, 0);
                acc = __builtin_amdgcn_mfma_f32_16x16x32_bf16(ah[s], bl[tt][s], acc, 0, 0, 0);
            }
            const int c = 16 * (w * 4 + tt) + lm;
            if (c < 240) {                   // skip zero-pad tile 15
                #pragma unroll
                for (int r = 0; r < 4; ++r)
                    gates[(lane >> 4) * 4 + r][c] = acc[r];
            }
        }
        __syncthreads();                     // gates ready; all U reads done

        // nonlinearity: thread (u=lane<60, rows w*4+r); i,j,f,o one float4
        if (lane < H_DIM) {
            #pragma unroll
            for (int r = 0; r < 4; ++r) {
                const int row = w * 4 + r;
                float4 gv = *reinterpret_cast<const float4*>(&gates[row][lane * 4]);
                float ig = fast_sig(gv.x);
                float jg = fast_tanh(gv.y);
                float fg = fast_sig(gv.z + 1.0f);    // forget bias
                float og = fast_sig(gv.w);
                cst[r] = cst[r] * fg + ig * jg;
                float h = fast_tanh(cst[r]) * og;
                unsigned short hh = bf16hi(h);
                Uhi[row][32 + lane] = (short)hh;
                Ulo[row][32 + lane] = (short)bf16hi(h - bf16tof(hh));
                if (t == T_STEPS - 1) hsf[row][lane] = h;
            }
        }
        // write x(t+1) into U from the prefetched registers
        if (tid < 128) {
            float vv[4] = {vx.x, vx.y, vx.z, vx.w};
            short4v hv, lv;
            #pragma unroll
            for (int j = 0; j < 4; ++j) {
                unsigned short hh = bf16hi(vv[j]);
                hv[j] = (short)hh;
                lv[j] = (short)bf16hi(vv[j] - bf16tof(hh));
            }
            *reinterpret_cast<short4v*>(&Uhi[prow][pkq * 4]) = hv;
            *reinterpret_cast<short4v*>(&Ulo[prow][pkq * 4]) = lv;
        }
        __syncthreads();                     // U(t+1) ready
    }

    // ---------------- epilogue: out[b] = h . dense_w + dense_b --------------
    if (tid < 16) {
        float acc = dense_b[0];
        #pragma unroll 4
        for (int uu = 0; uu < H_DIM; ++uu)
            acc = fmaf(hsf[tid][uu], dense_w[uu], acc);
        out[b0 + tid] = acc;
    }
}

extern "C" void kernel_launch(void* const* d_in, const int* in_sizes, int n_in,
                              void* d_out, int out_size, void* d_ws, size_t ws_size,
                              hipStream_t stream) {
    const float* x       = (const float*)d_in[0];
    const float* wk      = (const float*)d_in[1];
    const float* bias    = (const float*)d_in[2];
    const float* dense_w = (const float*)d_in[3];
    const float* dense_b = (const float*)d_in[4];
    float* out = (float*)d_out;

    lstm_mfma_kernel<<<B_TOTAL / 16, 256, 0, stream>>>(
        x, wk, bias, dense_w, dense_b, out);
}

// Round 3
// 660.812 us; speedup vs baseline: 2.9685x; 1.1300x over previous
//
#include <hip/hip_runtime.h>

typedef short short8  __attribute__((ext_vector_type(8)));
typedef short short4v __attribute__((ext_vector_type(4)));
typedef float f32x4   __attribute__((ext_vector_type(4)));

#define B_TOTAL 4096
#define T_STEPS 512
#define F_IN    32
#define H_DIM   60
#define KW      92      // F + H
#define GPAD    260     // gates row pitch (floats); cols 0..255 used
#define UPITCH  104     // U row pitch (halves); 96 used + pad for bank spread

__device__ __forceinline__ unsigned short bf16hi(float f) {
    unsigned int u = __float_as_uint(f);
    u += 0x7FFFu + ((u >> 16) & 1u);          // round to nearest even
    return (unsigned short)(u >> 16);
}
__device__ __forceinline__ float bf16tof(unsigned short s) {
    return __uint_as_float(((unsigned int)s) << 16);
}
__device__ __forceinline__ float fast_sig(float z) {
    return 1.0f / (1.0f + __expf(-z));
}
__device__ __forceinline__ float fast_tanh(float z) {
    return 1.0f - 2.0f / (1.0f + __expf(2.0f * z));
}

__global__ __launch_bounds__(512, 2)
void lstm_mfma_kernel(const float* __restrict__ x,
                      const float* __restrict__ wk,
                      const float* __restrict__ bias,
                      const float* __restrict__ dense_w,
                      const float* __restrict__ dense_b,
                      float* __restrict__ out)
{
    __shared__ float gates[16][GPAD];       // 16.6 KB, col c = u*4+gate
    __shared__ float hsf[16][64];           // final-step h (f32)
    __shared__ short Uhi[16][UPITCH];       // [x_t | h] bf16 hi, k padded to 96
    __shared__ short Ulo[16][UPITCH];       // bf16 lo (residual)

    const int tid  = threadIdx.x;
    const int lane = tid & 63;
    const int w    = tid >> 6;              // wave id 0..7
    const int b0   = blockIdx.x * 16;
    const int lm   = lane & 15;             // M/N lane index
    const int lk8  = (lane >> 4) * 8;       // K sub-block base

    // ---------------- prologue: B fragments (static weights) ----------------
    // Wave w owns N-tiles {2w, 2w+1}. Interleaved col c = u*4 + gate
    // (gate order i,j,f,o); original kernel layout is [k][gate*60 + u].
    // Each weight split into bf16 hi + lo.
    short8 bh[2][3], bl[2][3];
    float  biasv[2];
    #pragma unroll
    for (int tt = 0; tt < 2; ++tt) {
        const int n = w * 2 + tt;           // N-tile 0..15 (15 = zero pad)
        const int c = 16 * n + lm;
        const int u = c >> 2, g = c & 3;
        biasv[tt] = (c < 240) ? bias[g * 60 + u] : 0.0f;
        #pragma unroll
        for (int s = 0; s < 3; ++s) {
            short8 hv, lv;
            #pragma unroll
            for (int e = 0; e < 8; ++e) {
                const int k = s * 32 + lk8 + e;
                float wv = (k < KW && c < 240) ? wk[k * 240 + g * 60 + u] : 0.0f;
                unsigned short hh = bf16hi(wv);
                hv[e] = (short)hh;
                lv[e] = (short)bf16hi(wv - bf16tof(hh));
            }
            bh[tt][s] = hv;
            bl[tt][s] = lv;
        }
    }

    // ---------------- init U (zeros => h0 = 0 and K-pad = 0), stage x(0) ----
    for (int i = tid; i < 16 * UPITCH; i += 512) {
        (&Uhi[0][0])[i] = 0;
        (&Ulo[0][0])[i] = 0;
    }
    __syncthreads();
    if (tid < 128) {
        const int row = tid >> 3, kq = tid & 7;
        float4 v = *reinterpret_cast<const float4*>(
            x + (size_t)(b0 + row) * (T_STEPS * F_IN) + kq * 4);
        float vv[4] = {v.x, v.y, v.z, v.w};
        short4v hv, lv;
        #pragma unroll
        for (int j = 0; j < 4; ++j) {
            unsigned short hh = bf16hi(vv[j]);
            hv[j] = (short)hh;
            lv[j] = (short)bf16hi(vv[j] - bf16tof(hh));
        }
        *reinterpret_cast<short4v*>(&Uhi[row][kq * 4]) = hv;
        *reinterpret_cast<short4v*>(&Ulo[row][kq * 4]) = lv;
    }

    float cst[2] = {0.f, 0.f};              // cell state rows {2w, 2w+1}
    __syncthreads();

    // ---------------- T loop ----------------
    for (int t = 0; t < T_STEPS; ++t) {
        // prefetch x(t+1) -> registers (latency hides under MFMA + barrier)
        float4 vx;
        int prow = 0, pkq = 0;
        if (tid < 128) {
            prow = tid >> 3; pkq = tid & 7;
            const int tn = (t + 1 < T_STEPS) ? (t + 1) : t;
            vx = *reinterpret_cast<const float4*>(
                x + (size_t)(b0 + prow) * (T_STEPS * F_IN) + tn * F_IN + pkq * 4);
        }

        // A fragments (hi/lo) for the 3 K-steps — same for every wave
        short8 ah[3], al[3];
        #pragma unroll
        for (int s = 0; s < 3; ++s) {
            ah[s] = *reinterpret_cast<const short8*>(&Uhi[lm][s * 32 + lk8]);
            al[s] = *reinterpret_cast<const short8*>(&Ulo[lm][s * 32 + lk8]);
        }

        // gates = U @ W  (bf16x2: hi*hi + lo*hi + hi*lo), bias preloaded
        #pragma unroll
        for (int tt = 0; tt < 2; ++tt) {
            f32x4 acc = {biasv[tt], biasv[tt], biasv[tt], biasv[tt]};
            #pragma unroll
            for (int s = 0; s < 3; ++s) {
                acc = __builtin_amdgcn_mfma_f32_16x16x32_bf16(ah[s], bh[tt][s], acc, 0, 0, 0);
                acc = __builtin_amdgcn_mfma_f32_16x16x32_bf16(al[s], bh[tt][s], acc, 0, 0, 0);
                acc = __builtin_amdgcn_mfma_f32_16x16x32_bf16(ah[s], bl[tt][s], acc, 0, 0, 0);
            }
            const int c = 16 * (w * 2 + tt) + lm;
            if (c < 240) {                   // skip zero-pad tile 15
                #pragma unroll
                for (int r = 0; r < 4; ++r)
                    gates[(lane >> 4) * 4 + r][c] = acc[r];
            }
        }
        __syncthreads();                     // gates ready; all U reads done

        // nonlinearity: wave w rows {2w, 2w+1}; i,j,f,o one float4 per (row,u)
        if (lane < H_DIM) {
            #pragma unroll
            for (int r = 0; r < 2; ++r) {
                const int row = w * 2 + r;
                float4 gv = *reinterpret_cast<const float4*>(&gates[row][lane * 4]);
                float ig = fast_sig(gv.x);
                float jg = fast_tanh(gv.y);
                float fg = fast_sig(gv.z + 1.0f);    // forget bias
                float og = fast_sig(gv.w);
                cst[r] = cst[r] * fg + ig * jg;
                float h = fast_tanh(cst[r]) * og;
                unsigned short hh = bf16hi(h);
                Uhi[row][32 + lane] = (short)hh;
                Ulo[row][32 + lane] = (short)bf16hi(h - bf16tof(hh));
                if (t == T_STEPS - 1) hsf[row][lane] = h;
            }
        }
        // write x(t+1) into U from the prefetched registers
        if (tid < 128) {
            float vv[4] = {vx.x, vx.y, vx.z, vx.w};
            short4v hv, lv;
            #pragma unroll
            for (int j = 0; j < 4; ++j) {
                unsigned short hh = bf16hi(vv[j]);
                hv[j] = (short)hh;
                lv[j] = (short)bf16hi(vv[j] - bf16tof(hh));
            }
            *reinterpret_cast<short4v*>(&Uhi[prow][pkq * 4]) = hv;
            *reinterpret_cast<short4v*>(&Ulo[prow][pkq * 4]) = lv;
        }
        __syncthreads();                     // U(t+1) ready
    }

    // ---------------- epilogue: out[b] = h . dense_w + dense_b --------------
    if (tid < 16) {
        float acc = dense_b[0];
        #pragma unroll 4
        for (int uu = 0; uu < H_DIM; ++uu)
            acc = fmaf(hsf[tid][uu], dense_w[uu], acc);
        out[b0 + tid] = acc;
    }
}

extern "C" void kernel_launch(void* const* d_in, const int* in_sizes, int n_in,
                              void* d_out, int out_size, void* d_ws, size_t ws_size,
                              hipStream_t stream) {
    const float* x       = (const float*)d_in[0];
    const float* wk      = (const float*)d_in[1];
    const float* bias    = (const float*)d_in[2];
    const float* dense_w = (const float*)d_in[3];
    const float* dense_b = (const float*)d_in[4];
    float* out = (float*)d_out;

    lstm_mfma_kernel<<<B_TOTAL / 16, 512, 0, stream>>>(
        x, wk, bias, dense_w, dense_b, out);
}